// Round 4
// baseline (69.127 us; speedup 1.0000x reference)
//
#include <hip/hip_runtime.h>

#define DSZ 128
#define TX 16
#define TY 16
#define PY 24            // TY + 8 halo
#define NVOX 4194304.0f

__global__ void ncc_zero(float* out) { out[0] = 0.0f; }

__device__ __forceinline__ float4 f4add(const float4 a, const float4 b) {
    return make_float4(a.x + b.x, a.y + b.y, a.z + b.z, a.w + b.w);
}
__device__ __forceinline__ float4 f4sub(const float4 a, const float4 b) {
    return make_float4(a.x - b.x, a.y - b.y, a.z - b.z, a.w - b.w);
}

__global__ __launch_bounds__(256, 3) void ncc_main(const float* __restrict__ Iin,
                                                   const float* __restrict__ Jin,
                                                   float* __restrict__ out)
{
    const int tx0 = blockIdx.x * TX;
    const int ty0 = blockIdx.y * TY;
    const int b   = blockIdx.z >> 3;
    const int tz0 = (blockIdx.z & 7) * 16;
    const int tid = threadIdx.x;

    const float* __restrict__ Ib = Iin + b * (DSZ * DSZ * DSZ);
    const float* __restrict__ Jb = Jin + b * (DSZ * DSZ * DSZ);

    // x-summed moments, quad-buffered (1 barrier/round).
    __shared__ float4 s4m[4][PY][17];   // (sumI,sumJ,sumII,sumJJ)
    __shared__ float4 s1v[4][PY][5];    // sumIJ, 20 floats/row

    // Phase-B mapping (tid>=128): thread owns x=lxB, y in {2*ysB, 2*ysB+1}
    const int lxB = tid & 15;
    const int ysB = (tid >> 4) & 7;

    // ring-of-8 z-window state per column (compile-time indices via 4-round unroll)
    float4 rAv[8], rBv[8];
    float  rAs[8], rBs[8];
    float4 zA4 = make_float4(0.f, 0.f, 0.f, 0.f), zB4 = zA4;
    float  zA1 = 0.f, zB1 = 0.f;
#pragma unroll
    for (int i = 0; i < 8; ++i) {
        rAv[i] = make_float4(0.f, 0.f, 0.f, 0.f);
        rBv[i] = rAv[i];
        rAs[i] = 0.f; rBs[i] = 0.f;
    }
    float acc = 0.f;

    auto emit_cc = [&](const float4& z4, const float z1) {
        const float inv = 1.0f / 729.0f;
        const float uI = z4.x * inv;
        const float uJ = z4.y * inv;
        const float cross = z1 - uJ * z4.x - uI * z4.y + uI * uJ * 729.0f;
        const float Ivar  = z4.z - 2.0f * uI * z4.x + uI * uI * 729.0f;
        const float Jvar  = z4.w - 2.0f * uJ * z4.y + uJ * uJ * 729.0f;
        acc += cross * cross / (Ivar * Jvar + 1e-5f);
    };

    for (int mr = 0; mr < 3; ++mr) {           // 3 macro-rounds x 8 planes
#pragma unroll
        for (int r4 = 0; r4 < 4; ++r4) {       // 4 rounds x 2 planes
            // ---- Phase A: direct-from-global x-pass, planes t, t+1 ----
            if (tid < 192) {
                const int p   = (tid >= 96);
                const int t2  = tid - p * 96;
                const int r   = t2 >> 2;       // 0..23 halo row
                const int xg  = t2 & 3;        // group of 4 x-outputs
                const int zp  = tz0 + 8 * mr + 2 * r4 + p - 4;
                const int gy  = ty0 + r - 4;
                const int gxb = tx0 + 4 * xg - 4;
                const bool rowok = ((unsigned)zp < (unsigned)DSZ) &&
                                   ((unsigned)gy < (unsigned)DSZ);
                const int zoff = (zp * DSZ + gy) * DSZ;

                float vi[12], vj[12];
#pragma unroll
                for (int g = 0; g < 3; ++g) {
                    const int gx = gxb + 4 * g;
                    float4 va = make_float4(0.f, 0.f, 0.f, 0.f);
                    float4 vb = va;
                    if (rowok && (unsigned)gx < (unsigned)DSZ) {
                        va = *(const float4*)(Ib + zoff + gx);
                        vb = *(const float4*)(Jb + zoff + gx);
                    }
                    vi[4*g+0]=va.x; vi[4*g+1]=va.y; vi[4*g+2]=va.z; vi[4*g+3]=va.w;
                    vj[4*g+0]=vb.x; vj[4*g+1]=vb.y; vj[4*g+2]=vb.z; vj[4*g+3]=vb.w;
                }

                float wI=0.f, wJ=0.f, wII=0.f, wJJ=0.f, wIJ=0.f;
#pragma unroll
                for (int k = 0; k < 9; ++k) {
                    wI += vi[k]; wJ += vj[k];
                    wII = fmaf(vi[k], vi[k], wII);
                    wJJ = fmaf(vj[k], vj[k], wJJ);
                    wIJ = fmaf(vi[k], vj[k], wIJ);
                }
                const int sl = (r4 & 1) * 2 + p;
                float mIJ[4];
                s4m[sl][r][4*xg] = make_float4(wI, wJ, wII, wJJ);
                mIJ[0] = wIJ;
#pragma unroll
                for (int j = 1; j < 4; ++j) {
                    const float ai = vi[8+j], aj = vj[8+j];
                    const float di = vi[j-1], dj = vj[j-1];
                    wI += ai - di; wJ += aj - dj;
                    wII += fmaf(ai, ai, -di * di);
                    wJJ += fmaf(aj, aj, -dj * dj);
                    wIJ += fmaf(ai, aj, -di * dj);
                    s4m[sl][r][4*xg + j] = make_float4(wI, wJ, wII, wJJ);
                    mIJ[j] = wIJ;
                }
                s1v[sl][r][xg] = make_float4(mIJ[0], mIJ[1], mIJ[2], mIJ[3]);
            }
            __syncthreads();

            // ---- Phase B: y-pass (2 y per thread) + ring z-window ----
            if (tid >= 128) {
#pragma unroll
                for (int p = 0; p < 2; ++p) {
                    const int sl = (r4 & 1) * 2 + p;
                    const int k  = (2 * r4 + p) & 7;   // compile-time ring slot

                    const float4 row0v = s4m[sl][2*ysB + 0][lxB];
                    const float  row0s = ((const float*)&s1v[sl][2*ysB + 0][0])[lxB];
                    float4 c4 = row0v;
                    float  c1 = row0s;
#pragma unroll
                    for (int dy = 1; dy < 9; ++dy) {
                        c4 = f4add(c4, s4m[sl][2*ysB + dy][lxB]);
                        c1 += ((const float*)&s1v[sl][2*ysB + dy][0])[lxB];
                    }
                    const float4 r9v = s4m[sl][2*ysB + 9][lxB];
                    const float  r9s = ((const float*)&s1v[sl][2*ysB + 9][0])[lxB];
                    const float4 d4 = f4add(f4sub(c4, row0v), r9v);
                    const float  d1 = c1 - row0s + r9s;

                    // column A (y = ty0 + 2*ysB)
                    zA4 = f4add(zA4, c4); zA1 += c1;
                    if (mr > 0) emit_cc(zA4, zA1);
                    zA4 = f4sub(zA4, rAv[k]); zA1 -= rAs[k];
                    rAv[k] = c4; rAs[k] = c1;

                    // column B (y = ty0 + 2*ysB + 1)
                    zB4 = f4add(zB4, d4); zB1 += d1;
                    if (mr > 0) emit_cc(zB4, zB1);
                    zB4 = f4sub(zB4, rBv[k]); zB1 -= rBs[k];
                    rBv[k] = d4; rBs[k] = d1;
                }
            }
        }
    }

    // block reduction: wave shuffle then cross-wave via LDS
#pragma unroll
    for (int off = 32; off > 0; off >>= 1) acc += __shfl_down(acc, off);
    __shared__ float wpart[4];
    if ((tid & 63) == 0) wpart[tid >> 6] = acc;
    __syncthreads();
    if (tid == 0) {
        const float s = wpart[0] + wpart[1] + wpart[2] + wpart[3];
        atomicAdd(out, s * (-1.0f / NVOX));
    }
}

extern "C" void kernel_launch(void* const* d_in, const int* in_sizes, int n_in,
                              void* d_out, int out_size, void* d_ws, size_t ws_size,
                              hipStream_t stream)
{
    // setup_inputs order: d_in[0] = y_pred (J), d_in[1] = y_true (I)
    const float* J = (const float*)d_in[0];
    const float* I = (const float*)d_in[1];
    float* out = (float*)d_out;

    ncc_zero<<<dim3(1), dim3(1), 0, stream>>>(out);
    dim3 grid(DSZ / TX, DSZ / TY, 2 * (DSZ / 16));  // 8 x 8 x 16 = 1024 blocks
    ncc_main<<<grid, dim3(256), 0, stream>>>(I, J, out);
}